// Round 3
// baseline (1128.953 us; speedup 1.0000x reference)
//
#include <hip/hip_runtime.h>

// EMD approx-match (Fan et al. approxmatch.cu), B=8, N=M=4096.
// Register-tiled (4 rows/thread per LDS read), fused passC(l)+passA(l+1),
// chunked LDS staging so 4 blocks/CU co-reside (16 waves/CU) -> latency-bound
// bubbles filled; cn==0 level pair handled without the second exp.

#define BB 8
#define NN 4096
#define MM 4096

constexpr int BLK   = 256;  // threads per block (4 waves)
constexpr int S     = 32;   // inner-loop split lanes per row-group
constexpr int R     = 4;    // rows per thread
constexpr int RPB   = (BLK / S) * R;   // 32 rows per block
constexpr int CHUNK = 2048; // LDS staging chunk of the inner dimension

#if defined(__has_builtin)
#if __has_builtin(__builtin_amdgcn_exp2f)
#define EXP2F(x) __builtin_amdgcn_exp2f(x)
#endif
#endif
#ifndef EXP2F
#define EXP2F(x) exp2f(x)
#endif

__global__ void emd_init(float* __restrict__ satl, float* __restrict__ satr,
                         float* __restrict__ bsum, float* __restrict__ out) {
    int i = blockIdx.x * blockDim.x + threadIdx.x;
    if (i < BB * NN) satl[i] = 1.0f;   // factorl = max(N,M)/N = 1
    if (i < BB * MM) satr[i] = 1.0f;   // factorr = 1
    if (i < BB)      bsum[i] = 0.0f;
    if (i == 0)      out[0]  = 0.0f;
}

// Pass A (first level only): sl[n] = satl[n] / (sum_m e*satr[m] + 1e-9)
__global__ __launch_bounds__(BLK, 4) void emd_passA(
        const float* __restrict__ xyz1, const float* __restrict__ xyz2,
        const float* __restrict__ satl, const float* __restrict__ satr,
        float* __restrict__ sl, float c) {
    __shared__ float4 q[CHUNK];                  // (x2,y2,z2,satr[m]) 32 KB
    const int b    = blockIdx.x / (NN / RPB);
    const int tile = blockIdx.x % (NN / RPB);
    const float* x2b = xyz2 + (size_t)b * MM * 3;
    const float* srb = satr + (size_t)b * MM;

    const int g = threadIdx.x / S, s = threadIdx.x % S;
    const int n0 = tile * RPB + g * R;
    const float* p = xyz1 + ((size_t)b * NN + n0) * 3;
    float x1[R], y1[R], z1[R], acc[R];
    #pragma unroll
    for (int r = 0; r < R; ++r) {
        x1[r] = p[3*r]; y1[r] = p[3*r+1]; z1[r] = p[3*r+2]; acc[r] = 0.0f;
    }

    for (int c0 = 0; c0 < MM; c0 += CHUNK) {
        __syncthreads();
        for (int m = threadIdx.x; m < CHUNK; m += BLK) {
            int mm = c0 + m;
            q[m] = make_float4(x2b[3*mm], x2b[3*mm+1], x2b[3*mm+2], srb[mm]);
        }
        __syncthreads();
        #pragma unroll 4
        for (int j = 0; j < CHUNK / S; ++j) {
            float4 v = q[j * S + s];
            #pragma unroll
            for (int r = 0; r < R; ++r) {
                float dx = x1[r]-v.x, dy = y1[r]-v.y, dz = z1[r]-v.z;
                float d2 = fmaf(dx, dx, fmaf(dy, dy, dz * dz));
                acc[r] = fmaf(EXP2F(c * d2), v.w, acc[r]);
            }
        }
    }
    #pragma unroll
    for (int r = 0; r < R; ++r) {
        acc[r] += __shfl_xor(acc[r], 1);
        acc[r] += __shfl_xor(acc[r], 2);
        acc[r] += __shfl_xor(acc[r], 4);
        acc[r] += __shfl_xor(acc[r], 8);
        acc[r] += __shfl_xor(acc[r], 16);
    }
    if (s == 0) {
        #pragma unroll
        for (int r = 0; r < R; ++r) {
            int gi = b * NN + n0 + r;
            sl[gi] = satl[gi] / (acc[r] + 1e-9f);
        }
    }
}

// Pass B: ss2[m] = satr[m]*sum_n e*sl[n]; fused ratio + satr update.
// When do_sum, also accumulates bsum[b] = sum_m satr_new[m] (for the cn==0 CA).
__global__ __launch_bounds__(BLK, 4) void emd_passB(
        const float* __restrict__ xyz1, const float* __restrict__ xyz2,
        const float* __restrict__ sl, float* __restrict__ satr,
        float* __restrict__ sr2, float* __restrict__ bsum,
        int do_sum, float c) {
    __shared__ float4 p[CHUNK];                  // (x1,y1,z1,sl[n]) 32 KB
    const int b    = blockIdx.x / (MM / RPB);
    const int tile = blockIdx.x % (MM / RPB);
    const float* x1b = xyz1 + (size_t)b * NN * 3;
    const float* slb = sl + (size_t)b * NN;

    const int g = threadIdx.x / S, s = threadIdx.x % S;
    const int m0 = tile * RPB + g * R;
    const float* qp = xyz2 + ((size_t)b * MM + m0) * 3;
    float x2[R], y2[R], z2[R], acc[R];
    #pragma unroll
    for (int r = 0; r < R; ++r) {
        x2[r] = qp[3*r]; y2[r] = qp[3*r+1]; z2[r] = qp[3*r+2]; acc[r] = 0.0f;
    }

    for (int c0 = 0; c0 < NN; c0 += CHUNK) {
        __syncthreads();
        for (int n = threadIdx.x; n < CHUNK; n += BLK) {
            int nn = c0 + n;
            p[n] = make_float4(x1b[3*nn], x1b[3*nn+1], x1b[3*nn+2], slb[nn]);
        }
        __syncthreads();
        #pragma unroll 4
        for (int j = 0; j < CHUNK / S; ++j) {
            float4 v = p[j * S + s];
            #pragma unroll
            for (int r = 0; r < R; ++r) {
                float dx = v.x-x2[r], dy = v.y-y2[r], dz = v.z-z2[r];
                float d2 = fmaf(dx, dx, fmaf(dy, dy, dz * dz));
                acc[r] = fmaf(EXP2F(c * d2), v.w, acc[r]);
            }
        }
    }
    #pragma unroll
    for (int r = 0; r < R; ++r) {
        acc[r] += __shfl_xor(acc[r], 1);
        acc[r] += __shfl_xor(acc[r], 2);
        acc[r] += __shfl_xor(acc[r], 4);
        acc[r] += __shfl_xor(acc[r], 8);
        acc[r] += __shfl_xor(acc[r], 16);
    }
    float part = 0.0f;
    if (s == 0) {
        #pragma unroll
        for (int r = 0; r < R; ++r) {
            int gi = b * MM + m0 + r;
            float sr    = satr[gi];
            float ss2   = acc[r] * sr;
            float ratio = fminf(sr / (ss2 + 1e-9f), 1.0f);
            float sn    = fmaxf(sr - ss2 * ratio, 0.0f);
            sr2[gi]  = sr * ratio;                    // satr_old * ratio (for CA)
            satr[gi] = sn;                            // next level's satr
            part += sn;
        }
    }
    if (do_sum) {
        part += __shfl_xor(part, 1);
        part += __shfl_xor(part, 2);
        part += __shfl_xor(part, 4);
        part += __shfl_xor(part, 8);
        part += __shfl_xor(part, 16);
        part += __shfl_xor(part, 32);
        if ((threadIdx.x & 63) == 0) atomicAdd(&bsum[b], part);
    }
}

// Fused pass C(level l) + pass A(level l+1).
// MODE 0: general (second exp with coefficient cn)
// MODE 1: cn == 0 (level pair -0.25 -> 0): acc2 = bsum[b], no second exp
// MODE 2: last level: no A-part at all
template<int MODE>
__global__ __launch_bounds__(BLK, 4) void emd_passCA(
        const float* __restrict__ xyz1, const float* __restrict__ xyz2,
        float* __restrict__ sl, float* __restrict__ satl,
        const float* __restrict__ sr2, const float* __restrict__ satr_next,
        const float* __restrict__ bsum, float* __restrict__ out,
        float cl, float cn) {
    __shared__ float4 q[CHUNK];                    // (x2,y2,z2,sr2[m]) 32 KB
    __shared__ float  srn[(MODE == 0) ? CHUNK : 1];// satr_next[m] 8 KB (MODE 0)
    const int b    = blockIdx.x / (NN / RPB);
    const int tile = blockIdx.x % (NN / RPB);
    const float* x2b = xyz2 + (size_t)b * MM * 3;
    const float* s2b = sr2 + (size_t)b * MM;
    const float* srb = satr_next + (size_t)b * MM;

    const int g = threadIdx.x / S, s = threadIdx.x % S;
    const int n0 = tile * RPB + g * R;
    const float* pp = xyz1 + ((size_t)b * NN + n0) * 3;
    float x1[R], y1[R], z1[R], rd[R], cost[R], acc2[R], slv[R];
    #pragma unroll
    for (int r = 0; r < R; ++r) {
        x1[r] = pp[3*r]; y1[r] = pp[3*r+1]; z1[r] = pp[3*r+2];
        rd[r] = 0.0f; cost[r] = 0.0f; acc2[r] = 0.0f;
        slv[r] = sl[b * NN + n0 + r];
    }

    for (int c0 = 0; c0 < MM; c0 += CHUNK) {
        __syncthreads();
        for (int m = threadIdx.x; m < CHUNK; m += BLK) {
            int mm = c0 + m;
            q[m] = make_float4(x2b[3*mm], x2b[3*mm+1], x2b[3*mm+2], s2b[mm]);
            if (MODE == 0) srn[m] = srb[mm];
        }
        __syncthreads();

        #pragma unroll 4
        for (int j = 0; j < CHUNK / S; ++j) {
            float4 v = q[j * S + s];
            float w2 = (MODE == 0) ? srn[j * S + s] : 0.0f;
            #pragma unroll
            for (int r = 0; r < R; ++r) {
                float dx = x1[r]-v.x, dy = y1[r]-v.y, dz = z1[r]-v.z;
                float d2 = fmaf(dx, dx, fmaf(dy, dy, dz * dz));
                float e  = EXP2F(cl * d2);
                float t  = e * v.w;             // e * satr_old*ratio
                rd[r] += t;
                cost[r] = fmaf(t, d2, cost[r]);
                if (MODE == 0)
                    acc2[r] = fmaf(EXP2F(cn * d2), w2, acc2[r]);
            }
        }
    }

    #pragma unroll
    for (int r = 0; r < R; ++r) {
        rd[r] += __shfl_xor(rd[r], 1);
        rd[r] += __shfl_xor(rd[r], 2);
        rd[r] += __shfl_xor(rd[r], 4);
        rd[r] += __shfl_xor(rd[r], 8);
        rd[r] += __shfl_xor(rd[r], 16);
        if (MODE == 0) {
            acc2[r] += __shfl_xor(acc2[r], 1);
            acc2[r] += __shfl_xor(acc2[r], 2);
            acc2[r] += __shfl_xor(acc2[r], 4);
            acc2[r] += __shfl_xor(acc2[r], 8);
            acc2[r] += __shfl_xor(acc2[r], 16);
        }
    }

    // cost: scale by per-row sl, sum rows, full-wave reduce, 1 atomic/wave
    float csum = 0.0f;
    #pragma unroll
    for (int r = 0; r < R; ++r) csum += cost[r] * slv[r];
    csum += __shfl_xor(csum, 1);
    csum += __shfl_xor(csum, 2);
    csum += __shfl_xor(csum, 4);
    csum += __shfl_xor(csum, 8);
    csum += __shfl_xor(csum, 16);
    csum += __shfl_xor(csum, 32);
    if ((threadIdx.x & 63) == 0)
        atomicAdd(out, csum * (1.0f / (float)(BB * NN)));

    if (s == 0) {
        float bs = (MODE == 1) ? bsum[b] : 0.0f;
        #pragma unroll
        for (int r = 0; r < R; ++r) {
            int gi = b * NN + n0 + r;
            float sa = fmaxf(satl[gi] - rd[r] * slv[r], 0.0f);
            satl[gi] = sa;
            if (MODE == 0) sl[gi] = sa / (acc2[r] + 1e-9f);
            if (MODE == 1) sl[gi] = sa / (bs + 1e-9f);
        }
    }
}

extern "C" void kernel_launch(void* const* d_in, const int* in_sizes, int n_in,
                              void* d_out, int out_size, void* d_ws, size_t ws_size,
                              hipStream_t stream) {
    const float* xyz1 = (const float*)d_in[0];   // [B,N,3]
    const float* xyz2 = (const float*)d_in[1];   // [B,M,3]
    float* out  = (float*)d_out;                 // scalar

    float* satl = (float*)d_ws;                  // B*N
    float* sl   = satl + BB * NN;                // B*N
    float* satr = sl   + BB * NN;                // B*M
    float* sr2  = satr + BB * MM;                // B*M
    float* bsum = sr2  + BB * MM;                // B

    emd_init<<<(BB * NN + 255) / 256, 256, 0, stream>>>(satl, satr, bsum, out);

    const double levels[10] = {-16384.0, -4096.0, -1024.0, -256.0, -64.0,
                               -16.0, -4.0, -1.0, -0.25, 0.0};
    const double LOG2E = 1.4426950408889634;
    float c[10];
    for (int l = 0; l < 10; ++l) c[l] = (float)(levels[l] * LOG2E);

    const int grid = BB * (NN / RPB);   // 1024 blocks = 4 per CU

    emd_passA<<<grid, BLK, 0, stream>>>(xyz1, xyz2, satl, satr, sl, c[0]);
    for (int l = 0; l < 10; ++l) {
        emd_passB<<<grid, BLK, 0, stream>>>(xyz1, xyz2, sl, satr, sr2, bsum,
                                            (l == 8) ? 1 : 0, c[l]);
        if (l < 8)
            emd_passCA<0><<<grid, BLK, 0, stream>>>(
                xyz1, xyz2, sl, satl, sr2, satr, bsum, out, c[l], c[l + 1]);
        else if (l == 8)
            emd_passCA<1><<<grid, BLK, 0, stream>>>(
                xyz1, xyz2, sl, satl, sr2, satr, bsum, out, c[l], 0.0f);
        else
            emd_passCA<2><<<grid, BLK, 0, stream>>>(
                xyz1, xyz2, sl, satl, sr2, satr, bsum, out, c[l], 0.0f);
    }
}

// Round 4
// 1023.517 us; speedup vs baseline: 1.1030x; 1.1030x over previous
//
#include <hip/hip_runtime.h>

// EMD approx-match (Fan et al. approxmatch.cu), B=8, N=M=4096.
// Trans-pipe-bound -> minimize v_exp_f32 per element:
//  - CA fuses C(l)+A(l+1) with e_l = (exp2(cn*d2))^4   (1 exp, not 2)
//  - dot-form d2 with log2(weight) folded into the exp argument (A/B: 6 VALU+1 exp)
//  - level 9 (coef 0) collapsed to closed form (no [N,M] sweep at all)

#define BB 8
#define NN 4096
#define MM 4096

constexpr int BLK   = 256;  // threads per block (4 waves)
constexpr int S     = 32;   // inner-loop split lanes per row-group
constexpr int R     = 4;    // rows per thread
constexpr int RPB   = (BLK / S) * R;   // 32 rows per block
constexpr int CHUNK = 2048; // LDS staging chunk

#if defined(__has_builtin)
#if __has_builtin(__builtin_amdgcn_exp2f)
#define EXP2F(x) __builtin_amdgcn_exp2f(x)
#endif
#if __has_builtin(__builtin_amdgcn_logf)
#define LOG2F(x) __builtin_amdgcn_logf(x)
#endif
#endif
#ifndef EXP2F
#define EXP2F(x) exp2f(x)
#endif
#ifndef LOG2F
#define LOG2F(x) log2f(x)
#endif

__global__ void emd_init(float* __restrict__ satl, float* __restrict__ satr,
                         float* __restrict__ bsum, float* __restrict__ slsum,
                         float* __restrict__ scal, float* __restrict__ out) {
    int i = blockIdx.x * blockDim.x + threadIdx.x;
    if (i < BB * NN) satl[i] = 1.0f;
    if (i < BB * MM) satr[i] = 1.0f;
    if (i < BB)      bsum[i] = 0.0f;
    if (i < BB)      slsum[i] = 0.0f;
    if (i < BB * 5)  scal[i] = 0.0f;
    if (i == 0)      out[0]  = 0.0f;
}

// Pass A (level 0 only): sl[n] = satl[n] / (sum_m exp2(c*d2)*satr[m] + 1e-9)
// staged w = c*qq + log2(satr[m]); arg = w + c*pp - 2c*dot
__global__ __launch_bounds__(BLK, 4) void emd_passA(
        const float* __restrict__ xyz1, const float* __restrict__ xyz2,
        const float* __restrict__ satl, const float* __restrict__ satr,
        float* __restrict__ sl, float c) {
    __shared__ float4 q[CHUNK];                  // 32 KB
    const int b    = blockIdx.x / (NN / RPB);
    const int tile = blockIdx.x % (NN / RPB);
    const float* x2b = xyz2 + (size_t)b * MM * 3;
    const float* srb = satr + (size_t)b * MM;

    const int g = threadIdx.x / S, s = threadIdx.x % S;
    const int n0 = tile * RPB + g * R;
    const float* p = xyz1 + ((size_t)b * NN + n0) * 3;
    const float m2c = -2.0f * c;
    float x1[R], y1[R], z1[R], cpp[R], acc[R];
    #pragma unroll
    for (int r = 0; r < R; ++r) {
        x1[r] = p[3*r]; y1[r] = p[3*r+1]; z1[r] = p[3*r+2];
        cpp[r] = c * (x1[r]*x1[r] + y1[r]*y1[r] + z1[r]*z1[r]);
        acc[r] = 0.0f;
    }

    for (int c0 = 0; c0 < MM; c0 += CHUNK) {
        __syncthreads();
        for (int m = threadIdx.x; m < CHUNK; m += BLK) {
            int mm = c0 + m;
            float xx = x2b[3*mm], yy = x2b[3*mm+1], zz = x2b[3*mm+2];
            float qq = xx*xx + yy*yy + zz*zz;
            q[m] = make_float4(xx, yy, zz, fmaf(c, qq, LOG2F(srb[mm])));
        }
        __syncthreads();
        #pragma unroll 4
        for (int j = 0; j < CHUNK / S; ++j) {
            float4 v = q[j * S + s];
            #pragma unroll
            for (int r = 0; r < R; ++r) {
                float dot = fmaf(z1[r], v.z, fmaf(y1[r], v.y, x1[r]*v.x));
                float arg = fmaf(m2c, dot, v.w + cpp[r]);
                acc[r] += EXP2F(arg);
            }
        }
    }
    #pragma unroll
    for (int r = 0; r < R; ++r) {
        acc[r] += __shfl_xor(acc[r], 1);
        acc[r] += __shfl_xor(acc[r], 2);
        acc[r] += __shfl_xor(acc[r], 4);
        acc[r] += __shfl_xor(acc[r], 8);
        acc[r] += __shfl_xor(acc[r], 16);
    }
    if (s == 0) {
        #pragma unroll
        for (int r = 0; r < R; ++r) {
            int gi = b * NN + n0 + r;
            sl[gi] = satl[gi] / (acc[r] + 1e-9f);
        }
    }
}

// Pass B: colsum acc = sum_n exp2(c*d2)*sl[n]; fused ratio + satr update.
// staged w = c*pp + log2(sl[n]); register side owns columns m.
__global__ __launch_bounds__(BLK, 4) void emd_passB(
        const float* __restrict__ xyz1, const float* __restrict__ xyz2,
        const float* __restrict__ sl, float* __restrict__ satr,
        float* __restrict__ sr2, float* __restrict__ bsum,
        int do_sum, float c) {
    __shared__ float4 p[CHUNK];                  // 32 KB
    const int b    = blockIdx.x / (MM / RPB);
    const int tile = blockIdx.x % (MM / RPB);
    const float* x1b = xyz1 + (size_t)b * NN * 3;
    const float* slb = sl + (size_t)b * NN;

    const int g = threadIdx.x / S, s = threadIdx.x % S;
    const int m0 = tile * RPB + g * R;
    const float* qp = xyz2 + ((size_t)b * MM + m0) * 3;
    const float m2c = -2.0f * c;
    float x2[R], y2[R], z2[R], cqq[R], acc[R];
    #pragma unroll
    for (int r = 0; r < R; ++r) {
        x2[r] = qp[3*r]; y2[r] = qp[3*r+1]; z2[r] = qp[3*r+2];
        cqq[r] = c * (x2[r]*x2[r] + y2[r]*y2[r] + z2[r]*z2[r]);
        acc[r] = 0.0f;
    }

    for (int c0 = 0; c0 < NN; c0 += CHUNK) {
        __syncthreads();
        for (int n = threadIdx.x; n < CHUNK; n += BLK) {
            int nn = c0 + n;
            float xx = x1b[3*nn], yy = x1b[3*nn+1], zz = x1b[3*nn+2];
            float pp = xx*xx + yy*yy + zz*zz;
            p[n] = make_float4(xx, yy, zz, fmaf(c, pp, LOG2F(slb[nn])));
        }
        __syncthreads();
        #pragma unroll 4
        for (int j = 0; j < CHUNK / S; ++j) {
            float4 v = p[j * S + s];
            #pragma unroll
            for (int r = 0; r < R; ++r) {
                float dot = fmaf(z2[r], v.z, fmaf(y2[r], v.y, x2[r]*v.x));
                float arg = fmaf(m2c, dot, v.w + cqq[r]);
                acc[r] += EXP2F(arg);
            }
        }
    }
    #pragma unroll
    for (int r = 0; r < R; ++r) {
        acc[r] += __shfl_xor(acc[r], 1);
        acc[r] += __shfl_xor(acc[r], 2);
        acc[r] += __shfl_xor(acc[r], 4);
        acc[r] += __shfl_xor(acc[r], 8);
        acc[r] += __shfl_xor(acc[r], 16);
    }
    float part = 0.0f;
    if (s == 0) {
        #pragma unroll
        for (int r = 0; r < R; ++r) {
            int gi = b * MM + m0 + r;
            float sr    = satr[gi];
            float ss2   = acc[r] * sr;
            float ratio = fminf(sr / (ss2 + 1e-9f), 1.0f);
            float sn    = fmaxf(sr - ss2 * ratio, 0.0f);
            sr2[gi]  = sr * ratio;
            satr[gi] = sn;
            part += sn;
        }
    }
    if (do_sum) {
        part += __shfl_xor(part, 1);
        part += __shfl_xor(part, 2);
        part += __shfl_xor(part, 4);
        part += __shfl_xor(part, 8);
        part += __shfl_xor(part, 16);
        part += __shfl_xor(part, 32);
        if ((threadIdx.x & 63) == 0) atomicAdd(&bsum[b], part);
    }
}

// Fused C(l)+A(l+1), levels l=0..7 (cl = 4*cn). ONE exp per element:
// e_n = exp2(cn*d2); e_l = e_n^4; d2 recovered as arg/cn (cost via sum t*arg).
__global__ __launch_bounds__(BLK, 3) void emd_passCA0(
        const float* __restrict__ xyz1, const float* __restrict__ xyz2,
        float* __restrict__ sl, float* __restrict__ satl,
        const float* __restrict__ sr2, const float* __restrict__ satr_next,
        float* __restrict__ out, float cl, float cn) {
    __shared__ float4 q[CHUNK];    // (x2,y2,z2, cn*qq) 32 KB
    __shared__ float2 w[CHUNK];    // (sr2[m], satr_next[m]) 16 KB
    const int b    = blockIdx.x / (NN / RPB);
    const int tile = blockIdx.x % (NN / RPB);
    const float* x2b = xyz2 + (size_t)b * MM * 3;
    const float* s2b = sr2 + (size_t)b * MM;
    const float* srb = satr_next + (size_t)b * MM;

    const int g = threadIdx.x / S, s = threadIdx.x % S;
    const int n0 = tile * RPB + g * R;
    const float* pp_ = xyz1 + ((size_t)b * NN + n0) * 3;
    const float m2cn = -2.0f * cn;
    const float icn  = 1.0f / cn;
    float x1[R], y1[R], z1[R], cnpp[R], rd[R], costA[R], acc2[R], slv[R];
    #pragma unroll
    for (int r = 0; r < R; ++r) {
        x1[r] = pp_[3*r]; y1[r] = pp_[3*r+1]; z1[r] = pp_[3*r+2];
        cnpp[r] = cn * (x1[r]*x1[r] + y1[r]*y1[r] + z1[r]*z1[r]);
        rd[r] = 0.0f; costA[r] = 0.0f; acc2[r] = 0.0f;
        slv[r] = sl[b * NN + n0 + r];
    }

    for (int c0 = 0; c0 < MM; c0 += CHUNK) {
        __syncthreads();
        for (int m = threadIdx.x; m < CHUNK; m += BLK) {
            int mm = c0 + m;
            float xx = x2b[3*mm], yy = x2b[3*mm+1], zz = x2b[3*mm+2];
            float qq = xx*xx + yy*yy + zz*zz;
            q[m] = make_float4(xx, yy, zz, cn * qq);
            w[m] = make_float2(s2b[mm], srb[mm]);
        }
        __syncthreads();

        #pragma unroll 4
        for (int j = 0; j < CHUNK / S; ++j) {
            float4 v  = q[j * S + s];
            float2 wv = w[j * S + s];
            #pragma unroll
            for (int r = 0; r < R; ++r) {
                float dot = fmaf(z1[r], v.z, fmaf(y1[r], v.y, x1[r]*v.x));
                float arg = fmaf(m2cn, dot, v.w + cnpp[r]);   // cn*d2
                float en  = EXP2F(arg);
                acc2[r] = fmaf(en, wv.y, acc2[r]);            // A(l+1) rowsum
                float e2 = en * en;
                float t  = (e2 * e2) * wv.x;                  // e_l * sr2
                rd[r]   += t;
                costA[r] = fmaf(t, arg, costA[r]);            // t*(cn*d2)
            }
        }
    }

    #pragma unroll
    for (int r = 0; r < R; ++r) {
        rd[r] += __shfl_xor(rd[r], 1);
        rd[r] += __shfl_xor(rd[r], 2);
        rd[r] += __shfl_xor(rd[r], 4);
        rd[r] += __shfl_xor(rd[r], 8);
        rd[r] += __shfl_xor(rd[r], 16);
        acc2[r] += __shfl_xor(acc2[r], 1);
        acc2[r] += __shfl_xor(acc2[r], 2);
        acc2[r] += __shfl_xor(acc2[r], 4);
        acc2[r] += __shfl_xor(acc2[r], 8);
        acc2[r] += __shfl_xor(acc2[r], 16);
    }

    float csum = 0.0f;
    #pragma unroll
    for (int r = 0; r < R; ++r) csum += (costA[r] * icn) * slv[r];
    csum += __shfl_xor(csum, 1);
    csum += __shfl_xor(csum, 2);
    csum += __shfl_xor(csum, 4);
    csum += __shfl_xor(csum, 8);
    csum += __shfl_xor(csum, 16);
    csum += __shfl_xor(csum, 32);
    if ((threadIdx.x & 63) == 0)
        atomicAdd(out, csum * (1.0f / (float)(BB * NN)));

    if (s == 0) {
        #pragma unroll
        for (int r = 0; r < R; ++r) {
            int gi = b * NN + n0 + r;
            float sa = fmaxf(satl[gi] - rd[r] * slv[r], 0.0f);
            satl[gi] = sa;
            sl[gi] = sa / (acc2[r] + 1e-9f);
        }
    }
}

// Fused C(8)+A(9): cn==0 so A(9) denom = bsum[b]; single folded exp;
// also accumulates slsum[b] = sum_n sl9[n] for the closed-form level 9.
__global__ __launch_bounds__(BLK, 4) void emd_passCA1(
        const float* __restrict__ xyz1, const float* __restrict__ xyz2,
        float* __restrict__ sl, float* __restrict__ satl,
        const float* __restrict__ sr2, const float* __restrict__ bsum,
        float* __restrict__ slsum, float* __restrict__ out, float cl) {
    __shared__ float4 q[CHUNK];    // (x2,y2,z2, cl*qq + log2(sr2)) 32 KB
    __shared__ float  qa[CHUNK];   // qq                             8 KB
    const int b    = blockIdx.x / (NN / RPB);
    const int tile = blockIdx.x % (NN / RPB);
    const float* x2b = xyz2 + (size_t)b * MM * 3;
    const float* s2b = sr2 + (size_t)b * MM;

    const int g = threadIdx.x / S, s = threadIdx.x % S;
    const int n0 = tile * RPB + g * R;
    const float* pp_ = xyz1 + ((size_t)b * NN + n0) * 3;
    const float m2cl = -2.0f * cl;
    float x1[R], y1[R], z1[R], pp[R], clpp[R], rd[R], cost[R], slv[R];
    #pragma unroll
    for (int r = 0; r < R; ++r) {
        x1[r] = pp_[3*r]; y1[r] = pp_[3*r+1]; z1[r] = pp_[3*r+2];
        pp[r]   = x1[r]*x1[r] + y1[r]*y1[r] + z1[r]*z1[r];
        clpp[r] = cl * pp[r];
        rd[r] = 0.0f; cost[r] = 0.0f;
        slv[r] = sl[b * NN + n0 + r];
    }

    for (int c0 = 0; c0 < MM; c0 += CHUNK) {
        __syncthreads();
        for (int m = threadIdx.x; m < CHUNK; m += BLK) {
            int mm = c0 + m;
            float xx = x2b[3*mm], yy = x2b[3*mm+1], zz = x2b[3*mm+2];
            float qq = xx*xx + yy*yy + zz*zz;
            q[m]  = make_float4(xx, yy, zz, fmaf(cl, qq, LOG2F(s2b[mm])));
            qa[m] = qq;
        }
        __syncthreads();

        #pragma unroll 4
        for (int j = 0; j < CHUNK / S; ++j) {
            float4 v = q[j * S + s];
            float qq = qa[j * S + s];
            #pragma unroll
            for (int r = 0; r < R; ++r) {
                float dot = fmaf(z1[r], v.z, fmaf(y1[r], v.y, x1[r]*v.x));
                float t   = EXP2F(fmaf(m2cl, dot, v.w + clpp[r])); // e_l*sr2
                rd[r] += t;
                float d2 = fmaf(-2.0f, dot, pp[r]) + qq;
                cost[r] = fmaf(t, d2, cost[r]);
            }
        }
    }

    #pragma unroll
    for (int r = 0; r < R; ++r) {
        rd[r] += __shfl_xor(rd[r], 1);
        rd[r] += __shfl_xor(rd[r], 2);
        rd[r] += __shfl_xor(rd[r], 4);
        rd[r] += __shfl_xor(rd[r], 8);
        rd[r] += __shfl_xor(rd[r], 16);
    }

    float csum = 0.0f;
    #pragma unroll
    for (int r = 0; r < R; ++r) csum += cost[r] * slv[r];
    csum += __shfl_xor(csum, 1);
    csum += __shfl_xor(csum, 2);
    csum += __shfl_xor(csum, 4);
    csum += __shfl_xor(csum, 8);
    csum += __shfl_xor(csum, 16);
    csum += __shfl_xor(csum, 32);
    if ((threadIdx.x & 63) == 0)
        atomicAdd(out, csum * (1.0f / (float)(BB * NN)));

    float part = 0.0f;
    if (s == 0) {
        float bs = bsum[b];
        #pragma unroll
        for (int r = 0; r < R; ++r) {
            int gi = b * NN + n0 + r;
            float sa = fmaxf(satl[gi] - rd[r] * slv[r], 0.0f);
            satl[gi] = sa;
            float s9 = sa / (bs + 1e-9f);
            sl[gi] = s9;
            part += s9;
        }
    }
    part += __shfl_xor(part, 1);
    part += __shfl_xor(part, 2);
    part += __shfl_xor(part, 4);
    part += __shfl_xor(part, 8);
    part += __shfl_xor(part, 16);
    part += __shfl_xor(part, 32);
    if ((threadIdx.x & 63) == 0) atomicAdd(&slsum[b], part);
}

// Level 9 (coef 0): sr2_9[m] = satr9[m]*min(1/(satr9[m]*SL9+1e-9)*satr9[m],1)...
// computed directly; accumulate 5 moments of xyz2 weighted by sr2_9.
__global__ void emd_lvl9_col(const float* __restrict__ xyz2,
                             const float* __restrict__ satr,
                             const float* __restrict__ slsum,
                             float* __restrict__ scal) {
    int i = blockIdx.x * blockDim.x + threadIdx.x;   // over B*M
    int b = i / MM;
    const float* qp = xyz2 + (size_t)i * 3;
    float sr = satr[i];
    float ss2 = sr * slsum[b];
    float ratio = fminf(sr / (ss2 + 1e-9f), 1.0f);
    float s2 = sr * ratio;
    float x = qp[0], y = qp[1], z = qp[2];
    float v0 = s2, v1 = s2*x, v2 = s2*y, v3 = s2*z;
    float v4 = s2 * (x*x + y*y + z*z);
    #pragma unroll
    for (int d = 1; d < 64; d <<= 1) {
        v0 += __shfl_xor(v0, d); v1 += __shfl_xor(v1, d);
        v2 += __shfl_xor(v2, d); v3 += __shfl_xor(v3, d);
        v4 += __shfl_xor(v4, d);
    }
    if ((threadIdx.x & 63) == 0) {
        atomicAdd(&scal[b*5+0], v0); atomicAdd(&scal[b*5+1], v1);
        atomicAdd(&scal[b*5+2], v2); atomicAdd(&scal[b*5+3], v3);
        atomicAdd(&scal[b*5+4], v4);
    }
}

__global__ void emd_lvl9_cost(const float* __restrict__ xyz1,
                              const float* __restrict__ sl,
                              const float* __restrict__ scal,
                              float* __restrict__ out) {
    int i = blockIdx.x * blockDim.x + threadIdx.x;   // over B*N
    int b = i / NN;
    float W  = scal[b*5+0], Wx = scal[b*5+1], Wy = scal[b*5+2];
    float Wz = scal[b*5+3], Q  = scal[b*5+4];
    const float* p = xyz1 + (size_t)i * 3;
    float x = p[0], y = p[1], z = p[2];
    float pp = x*x + y*y + z*z;
    float dotw = x*Wx + y*Wy + z*Wz;
    float c = sl[i] * (pp * W + Q - 2.0f * dotw);
    #pragma unroll
    for (int d = 1; d < 64; d <<= 1) c += __shfl_xor(c, d);
    if ((threadIdx.x & 63) == 0)
        atomicAdd(out, c * (1.0f / (float)(BB * NN)));
}

extern "C" void kernel_launch(void* const* d_in, const int* in_sizes, int n_in,
                              void* d_out, int out_size, void* d_ws, size_t ws_size,
                              hipStream_t stream) {
    const float* xyz1 = (const float*)d_in[0];   // [B,N,3]
    const float* xyz2 = (const float*)d_in[1];   // [B,M,3]
    float* out  = (float*)d_out;                 // scalar

    float* satl  = (float*)d_ws;                 // B*N
    float* sl    = satl  + BB * NN;              // B*N
    float* satr  = sl    + BB * NN;              // B*M
    float* sr2   = satr  + BB * MM;              // B*M
    float* bsum  = sr2   + BB * MM;              // B
    float* slsum = bsum  + BB;                   // B
    float* scal  = slsum + BB;                   // B*5

    emd_init<<<(BB * NN + 255) / 256, 256, 0, stream>>>(satl, satr, bsum,
                                                        slsum, scal, out);

    const double levels[10] = {-16384.0, -4096.0, -1024.0, -256.0, -64.0,
                               -16.0, -4.0, -1.0, -0.25, 0.0};
    const double LOG2E = 1.4426950408889634;
    float c[10];
    for (int l = 0; l < 10; ++l) c[l] = (float)(levels[l] * LOG2E);

    const int grid = BB * (NN / RPB);   // 1024 blocks

    emd_passA<<<grid, BLK, 0, stream>>>(xyz1, xyz2, satl, satr, sl, c[0]);
    for (int l = 0; l <= 8; ++l) {
        emd_passB<<<grid, BLK, 0, stream>>>(xyz1, xyz2, sl, satr, sr2, bsum,
                                            (l == 8) ? 1 : 0, c[l]);
        if (l < 8)
            emd_passCA0<<<grid, BLK, 0, stream>>>(
                xyz1, xyz2, sl, satl, sr2, satr, out, c[l], c[l + 1]);
        else
            emd_passCA1<<<grid, BLK, 0, stream>>>(
                xyz1, xyz2, sl, satl, sr2, bsum, slsum, out, c[l]);
    }
    emd_lvl9_col<<<BB * MM / 256, 256, 0, stream>>>(xyz2, satr, slsum, scal);
    emd_lvl9_cost<<<BB * NN / 256, 256, 0, stream>>>(xyz1, sl, scal, out);
}

// Round 5
// 898.441 us; speedup vs baseline: 1.2566x; 1.1392x over previous
//
#include <hip/hip_runtime.h>

// EMD approx-match (Fan et al. approxmatch.cu), B=8, N=M=4096.
// Latency-bound fix: software-pipelined register prefetch (double-buffered
// groups of 4 LDS reads) + S=16 broadcast-friendly LDS access pattern.
// Structure: A(0); per level: B sweep + fused C(l)/A(l+1) sweep; level 9
// (coef 0) in closed form.

#define BB 8
#define NN 4096
#define MM 4096

constexpr int BLK   = 256;  // threads per block (4 waves)
constexpr int S     = 16;   // inner-loop split lanes per row-group
constexpr int R     = 4;    // rows per thread
constexpr int RPB   = (BLK / S) * R;   // 64 rows per block
constexpr int CHUNK = 2048; // LDS staging chunk
constexpr int G     = (CHUNK / S) / 4; // 32 groups of 4 j-iters

#if defined(__has_builtin)
#if __has_builtin(__builtin_amdgcn_exp2f)
#define EXP2F(x) __builtin_amdgcn_exp2f(x)
#endif
#if __has_builtin(__builtin_amdgcn_logf)
#define LOG2F(x) __builtin_amdgcn_logf(x)
#endif
#endif
#ifndef EXP2F
#define EXP2F(x) exp2f(x)
#endif
#ifndef LOG2F
#define LOG2F(x) log2f(x)
#endif

__global__ void emd_init(float* __restrict__ satl, float* __restrict__ satr,
                         float* __restrict__ bsum, float* __restrict__ slsum,
                         float* __restrict__ scal, float* __restrict__ out) {
    int i = blockIdx.x * blockDim.x + threadIdx.x;
    if (i < BB * NN) satl[i] = 1.0f;
    if (i < BB * MM) satr[i] = 1.0f;
    if (i < BB)      bsum[i] = 0.0f;
    if (i < BB)      slsum[i] = 0.0f;
    if (i < BB * 5)  scal[i] = 0.0f;
    if (i == 0)      out[0]  = 0.0f;
}

// ---------- Pass A (level 0 only): sl[n] = satl[n]/(rowsum + 1e-9) ----------
// staged w = c*qq + log2(satr[m]); arg = w + c*pp - 2c*dot
#define A_LOAD(vv, gg)                                           \
    _Pragma("unroll")                                            \
    for (int k = 0; k < 4; ++k) vv[k] = q[((gg)*4 + k)*S + s];

#define A_COMP(vv)                                               \
    _Pragma("unroll")                                            \
    for (int k = 0; k < 4; ++k) {                                \
        float4 v = vv[k];                                        \
        _Pragma("unroll")                                        \
        for (int r = 0; r < R; ++r) {                            \
            float dot = fmaf(z1[r], v.z, fmaf(y1[r], v.y, x1[r]*v.x)); \
            float arg = fmaf(m2c, dot, v.w + cpp[r]);            \
            acc[r] += EXP2F(arg);                                \
        }                                                        \
    }

__global__ __launch_bounds__(BLK, 2) void emd_passA(
        const float* __restrict__ xyz1, const float* __restrict__ xyz2,
        const float* __restrict__ satl, const float* __restrict__ satr,
        float* __restrict__ sl, float c) {
    __shared__ float4 q[CHUNK];                  // 32 KB
    const int b    = blockIdx.x / (NN / RPB);
    const int tile = blockIdx.x % (NN / RPB);
    const float* x2b = xyz2 + (size_t)b * MM * 3;
    const float* srb = satr + (size_t)b * MM;

    const int g = threadIdx.x / S, s = threadIdx.x % S;
    const int n0 = tile * RPB + g * R;
    const float* p = xyz1 + ((size_t)b * NN + n0) * 3;
    const float m2c = -2.0f * c;
    float x1[R], y1[R], z1[R], cpp[R], acc[R];
    #pragma unroll
    for (int r = 0; r < R; ++r) {
        x1[r] = p[3*r]; y1[r] = p[3*r+1]; z1[r] = p[3*r+2];
        cpp[r] = c * (x1[r]*x1[r] + y1[r]*y1[r] + z1[r]*z1[r]);
        acc[r] = 0.0f;
    }

    for (int c0 = 0; c0 < MM; c0 += CHUNK) {
        __syncthreads();
        for (int m = threadIdx.x; m < CHUNK; m += BLK) {
            int mm = c0 + m;
            float xx = x2b[3*mm], yy = x2b[3*mm+1], zz = x2b[3*mm+2];
            float qq = xx*xx + yy*yy + zz*zz;
            q[m] = make_float4(xx, yy, zz, fmaf(c, qq, LOG2F(srb[mm])));
        }
        __syncthreads();
        float4 va[4], vb[4];
        A_LOAD(va, 0);
        #pragma unroll 1
        for (int gs = 0; gs < G; gs += 2) {
            A_LOAD(vb, gs + 1);
            A_COMP(va);
            if (gs + 2 < G) { A_LOAD(va, gs + 2); }
            A_COMP(vb);
        }
    }
    #pragma unroll
    for (int r = 0; r < R; ++r) {
        acc[r] += __shfl_xor(acc[r], 1);
        acc[r] += __shfl_xor(acc[r], 2);
        acc[r] += __shfl_xor(acc[r], 4);
        acc[r] += __shfl_xor(acc[r], 8);
    }
    if (s == 0) {
        #pragma unroll
        for (int r = 0; r < R; ++r) {
            int gi = b * NN + n0 + r;
            sl[gi] = satl[gi] / (acc[r] + 1e-9f);
        }
    }
}

// ---------- Pass B: colsum + fused ratio + satr update ----------
__global__ __launch_bounds__(BLK, 2) void emd_passB(
        const float* __restrict__ xyz1, const float* __restrict__ xyz2,
        const float* __restrict__ sl, float* __restrict__ satr,
        float* __restrict__ sr2, float* __restrict__ bsum,
        int do_sum, float c) {
    __shared__ float4 q[CHUNK];                  // 32 KB (rows n staged)
    const int b    = blockIdx.x / (MM / RPB);
    const int tile = blockIdx.x % (MM / RPB);
    const float* x1b = xyz1 + (size_t)b * NN * 3;
    const float* slb = sl + (size_t)b * NN;

    const int g = threadIdx.x / S, s = threadIdx.x % S;
    const int m0 = tile * RPB + g * R;
    const float* qp = xyz2 + ((size_t)b * MM + m0) * 3;
    const float m2c = -2.0f * c;
    float x1[R], y1[R], z1[R], cpp[R], acc[R];
    #pragma unroll
    for (int r = 0; r < R; ++r) {
        x1[r] = qp[3*r]; y1[r] = qp[3*r+1]; z1[r] = qp[3*r+2];
        cpp[r] = c * (x1[r]*x1[r] + y1[r]*y1[r] + z1[r]*z1[r]);
        acc[r] = 0.0f;
    }

    for (int c0 = 0; c0 < NN; c0 += CHUNK) {
        __syncthreads();
        for (int n = threadIdx.x; n < CHUNK; n += BLK) {
            int nn = c0 + n;
            float xx = x1b[3*nn], yy = x1b[3*nn+1], zz = x1b[3*nn+2];
            float pp = xx*xx + yy*yy + zz*zz;
            q[n] = make_float4(xx, yy, zz, fmaf(c, pp, LOG2F(slb[nn])));
        }
        __syncthreads();
        float4 va[4], vb[4];
        A_LOAD(va, 0);
        #pragma unroll 1
        for (int gs = 0; gs < G; gs += 2) {
            A_LOAD(vb, gs + 1);
            A_COMP(va);
            if (gs + 2 < G) { A_LOAD(va, gs + 2); }
            A_COMP(vb);
        }
    }
    #pragma unroll
    for (int r = 0; r < R; ++r) {
        acc[r] += __shfl_xor(acc[r], 1);
        acc[r] += __shfl_xor(acc[r], 2);
        acc[r] += __shfl_xor(acc[r], 4);
        acc[r] += __shfl_xor(acc[r], 8);
    }
    float part = 0.0f;
    if (s == 0) {
        #pragma unroll
        for (int r = 0; r < R; ++r) {
            int gi = b * MM + m0 + r;
            float sr    = satr[gi];
            float ss2   = acc[r] * sr;
            float ratio = fminf(sr / (ss2 + 1e-9f), 1.0f);
            float sn    = fmaxf(sr - ss2 * ratio, 0.0f);
            sr2[gi]  = sr * ratio;
            satr[gi] = sn;
            part += sn;
        }
    }
    if (do_sum) {
        part += __shfl_xor(part, 1);
        part += __shfl_xor(part, 2);
        part += __shfl_xor(part, 4);
        part += __shfl_xor(part, 8);
        part += __shfl_xor(part, 16);
        part += __shfl_xor(part, 32);
        if ((threadIdx.x & 63) == 0) atomicAdd(&bsum[b], part);
    }
}

// ---------- Fused C(l)+A(l+1), l=0..7 (cl = 4*cn): 1 exp/element ----------
#define CA0_LOAD(vv, ww, gg)                                     \
    _Pragma("unroll")                                            \
    for (int k = 0; k < 4; ++k) {                                \
        int idx = ((gg)*4 + k)*S + s;                            \
        vv[k] = q[idx]; ww[k] = w[idx];                          \
    }

#define CA0_COMP(vv, ww)                                         \
    _Pragma("unroll")                                            \
    for (int k = 0; k < 4; ++k) {                                \
        float4 v = vv[k]; float2 wv = ww[k];                     \
        _Pragma("unroll")                                        \
        for (int r = 0; r < R; ++r) {                            \
            float dot = fmaf(z1[r], v.z, fmaf(y1[r], v.y, x1[r]*v.x)); \
            float arg = fmaf(m2cn, dot, v.w + cnpp[r]);          \
            float en  = EXP2F(arg);                              \
            acc2[r] = fmaf(en, wv.y, acc2[r]);                   \
            float e2 = en * en;                                  \
            float t  = (e2 * e2) * wv.x;                         \
            rd[r]   += t;                                        \
            costA[r] = fmaf(t, arg, costA[r]);                   \
        }                                                        \
    }

__global__ __launch_bounds__(BLK, 2) void emd_passCA0(
        const float* __restrict__ xyz1, const float* __restrict__ xyz2,
        float* __restrict__ sl, float* __restrict__ satl,
        const float* __restrict__ sr2, const float* __restrict__ satr_next,
        float* __restrict__ out, float cl, float cn) {
    __shared__ float4 q[CHUNK];    // (x2,y2,z2, cn*qq) 32 KB
    __shared__ float2 w[CHUNK];    // (sr2[m], satr_next[m]) 16 KB
    const int b    = blockIdx.x / (NN / RPB);
    const int tile = blockIdx.x % (NN / RPB);
    const float* x2b = xyz2 + (size_t)b * MM * 3;
    const float* s2b = sr2 + (size_t)b * MM;
    const float* srb = satr_next + (size_t)b * MM;

    const int g = threadIdx.x / S, s = threadIdx.x % S;
    const int n0 = tile * RPB + g * R;
    const float* pp_ = xyz1 + ((size_t)b * NN + n0) * 3;
    const float m2cn = -2.0f * cn;
    const float icn  = 1.0f / cn;
    float x1[R], y1[R], z1[R], cnpp[R], rd[R], costA[R], acc2[R], slv[R];
    #pragma unroll
    for (int r = 0; r < R; ++r) {
        x1[r] = pp_[3*r]; y1[r] = pp_[3*r+1]; z1[r] = pp_[3*r+2];
        cnpp[r] = cn * (x1[r]*x1[r] + y1[r]*y1[r] + z1[r]*z1[r]);
        rd[r] = 0.0f; costA[r] = 0.0f; acc2[r] = 0.0f;
        slv[r] = sl[b * NN + n0 + r];
    }

    for (int c0 = 0; c0 < MM; c0 += CHUNK) {
        __syncthreads();
        for (int m = threadIdx.x; m < CHUNK; m += BLK) {
            int mm = c0 + m;
            float xx = x2b[3*mm], yy = x2b[3*mm+1], zz = x2b[3*mm+2];
            float qq = xx*xx + yy*yy + zz*zz;
            q[m] = make_float4(xx, yy, zz, cn * qq);
            w[m] = make_float2(s2b[mm], srb[mm]);
        }
        __syncthreads();

        float4 va[4], vb[4]; float2 wa[4], wb[4];
        CA0_LOAD(va, wa, 0);
        #pragma unroll 1
        for (int gs = 0; gs < G; gs += 2) {
            CA0_LOAD(vb, wb, gs + 1);
            CA0_COMP(va, wa);
            if (gs + 2 < G) { CA0_LOAD(va, wa, gs + 2); }
            CA0_COMP(vb, wb);
        }
    }

    #pragma unroll
    for (int r = 0; r < R; ++r) {
        rd[r] += __shfl_xor(rd[r], 1);
        rd[r] += __shfl_xor(rd[r], 2);
        rd[r] += __shfl_xor(rd[r], 4);
        rd[r] += __shfl_xor(rd[r], 8);
        acc2[r] += __shfl_xor(acc2[r], 1);
        acc2[r] += __shfl_xor(acc2[r], 2);
        acc2[r] += __shfl_xor(acc2[r], 4);
        acc2[r] += __shfl_xor(acc2[r], 8);
    }

    float csum = 0.0f;
    #pragma unroll
    for (int r = 0; r < R; ++r) csum += (costA[r] * icn) * slv[r];
    csum += __shfl_xor(csum, 1);
    csum += __shfl_xor(csum, 2);
    csum += __shfl_xor(csum, 4);
    csum += __shfl_xor(csum, 8);
    csum += __shfl_xor(csum, 16);
    csum += __shfl_xor(csum, 32);
    if ((threadIdx.x & 63) == 0)
        atomicAdd(out, csum * (1.0f / (float)(BB * NN)));

    if (s == 0) {
        #pragma unroll
        for (int r = 0; r < R; ++r) {
            int gi = b * NN + n0 + r;
            float sa = fmaxf(satl[gi] - rd[r] * slv[r], 0.0f);
            satl[gi] = sa;
            sl[gi] = sa / (acc2[r] + 1e-9f);
        }
    }
}

// ---------- Fused C(8)+A(9): cn==0 path; also accumulates slsum ----------
#define CA1_LOAD(vv, aa, gg)                                     \
    _Pragma("unroll")                                            \
    for (int k = 0; k < 4; ++k) {                                \
        int idx = ((gg)*4 + k)*S + s;                            \
        vv[k] = q[idx]; aa[k] = qa[idx];                         \
    }

#define CA1_COMP(vv, aa)                                         \
    _Pragma("unroll")                                            \
    for (int k = 0; k < 4; ++k) {                                \
        float4 v = vv[k]; float qq = aa[k];                      \
        _Pragma("unroll")                                        \
        for (int r = 0; r < R; ++r) {                            \
            float dot = fmaf(z1[r], v.z, fmaf(y1[r], v.y, x1[r]*v.x)); \
            float t   = EXP2F(fmaf(m2cl, dot, v.w + clpp[r]));   \
            rd[r] += t;                                          \
            float d2 = fmaf(-2.0f, dot, pp[r]) + qq;             \
            cost[r] = fmaf(t, d2, cost[r]);                      \
        }                                                        \
    }

__global__ __launch_bounds__(BLK, 2) void emd_passCA1(
        const float* __restrict__ xyz1, const float* __restrict__ xyz2,
        float* __restrict__ sl, float* __restrict__ satl,
        const float* __restrict__ sr2, const float* __restrict__ bsum,
        float* __restrict__ slsum, float* __restrict__ out, float cl) {
    __shared__ float4 q[CHUNK];    // (x2,y2,z2, cl*qq + log2(sr2)) 32 KB
    __shared__ float  qa[CHUNK];   // qq                             8 KB
    const int b    = blockIdx.x / (NN / RPB);
    const int tile = blockIdx.x % (NN / RPB);
    const float* x2b = xyz2 + (size_t)b * MM * 3;
    const float* s2b = sr2 + (size_t)b * MM;

    const int g = threadIdx.x / S, s = threadIdx.x % S;
    const int n0 = tile * RPB + g * R;
    const float* pp_ = xyz1 + ((size_t)b * NN + n0) * 3;
    const float m2cl = -2.0f * cl;
    float x1[R], y1[R], z1[R], pp[R], clpp[R], rd[R], cost[R], slv[R];
    #pragma unroll
    for (int r = 0; r < R; ++r) {
        x1[r] = pp_[3*r]; y1[r] = pp_[3*r+1]; z1[r] = pp_[3*r+2];
        pp[r]   = x1[r]*x1[r] + y1[r]*y1[r] + z1[r]*z1[r];
        clpp[r] = cl * pp[r];
        rd[r] = 0.0f; cost[r] = 0.0f;
        slv[r] = sl[b * NN + n0 + r];
    }

    for (int c0 = 0; c0 < MM; c0 += CHUNK) {
        __syncthreads();
        for (int m = threadIdx.x; m < CHUNK; m += BLK) {
            int mm = c0 + m;
            float xx = x2b[3*mm], yy = x2b[3*mm+1], zz = x2b[3*mm+2];
            float qq = xx*xx + yy*yy + zz*zz;
            q[m]  = make_float4(xx, yy, zz, fmaf(cl, qq, LOG2F(s2b[mm])));
            qa[m] = qq;
        }
        __syncthreads();

        float4 va[4], vb[4]; float aa[4], ab[4];
        CA1_LOAD(va, aa, 0);
        #pragma unroll 1
        for (int gs = 0; gs < G; gs += 2) {
            CA1_LOAD(vb, ab, gs + 1);
            CA1_COMP(va, aa);
            if (gs + 2 < G) { CA1_LOAD(va, aa, gs + 2); }
            CA1_COMP(vb, ab);
        }
    }

    #pragma unroll
    for (int r = 0; r < R; ++r) {
        rd[r] += __shfl_xor(rd[r], 1);
        rd[r] += __shfl_xor(rd[r], 2);
        rd[r] += __shfl_xor(rd[r], 4);
        rd[r] += __shfl_xor(rd[r], 8);
    }

    float csum = 0.0f;
    #pragma unroll
    for (int r = 0; r < R; ++r) csum += cost[r] * slv[r];
    csum += __shfl_xor(csum, 1);
    csum += __shfl_xor(csum, 2);
    csum += __shfl_xor(csum, 4);
    csum += __shfl_xor(csum, 8);
    csum += __shfl_xor(csum, 16);
    csum += __shfl_xor(csum, 32);
    if ((threadIdx.x & 63) == 0)
        atomicAdd(out, csum * (1.0f / (float)(BB * NN)));

    float part = 0.0f;
    if (s == 0) {
        float bs = bsum[b];
        #pragma unroll
        for (int r = 0; r < R; ++r) {
            int gi = b * NN + n0 + r;
            float sa = fmaxf(satl[gi] - rd[r] * slv[r], 0.0f);
            satl[gi] = sa;
            float s9 = sa / (bs + 1e-9f);
            sl[gi] = s9;
            part += s9;
        }
    }
    part += __shfl_xor(part, 1);
    part += __shfl_xor(part, 2);
    part += __shfl_xor(part, 4);
    part += __shfl_xor(part, 8);
    part += __shfl_xor(part, 16);
    part += __shfl_xor(part, 32);
    if ((threadIdx.x & 63) == 0) atomicAdd(&slsum[b], part);
}

// ---------- Level 9 (coef 0) closed form ----------
__global__ void emd_lvl9_col(const float* __restrict__ xyz2,
                             const float* __restrict__ satr,
                             const float* __restrict__ slsum,
                             float* __restrict__ scal) {
    int i = blockIdx.x * blockDim.x + threadIdx.x;   // over B*M
    int b = i / MM;
    const float* qp = xyz2 + (size_t)i * 3;
    float sr = satr[i];
    float ss2 = sr * slsum[b];
    float ratio = fminf(sr / (ss2 + 1e-9f), 1.0f);
    float s2 = sr * ratio;
    float x = qp[0], y = qp[1], z = qp[2];
    float v0 = s2, v1 = s2*x, v2 = s2*y, v3 = s2*z;
    float v4 = s2 * (x*x + y*y + z*z);
    #pragma unroll
    for (int d = 1; d < 64; d <<= 1) {
        v0 += __shfl_xor(v0, d); v1 += __shfl_xor(v1, d);
        v2 += __shfl_xor(v2, d); v3 += __shfl_xor(v3, d);
        v4 += __shfl_xor(v4, d);
    }
    if ((threadIdx.x & 63) == 0) {
        atomicAdd(&scal[b*5+0], v0); atomicAdd(&scal[b*5+1], v1);
        atomicAdd(&scal[b*5+2], v2); atomicAdd(&scal[b*5+3], v3);
        atomicAdd(&scal[b*5+4], v4);
    }
}

__global__ void emd_lvl9_cost(const float* __restrict__ xyz1,
                              const float* __restrict__ sl,
                              const float* __restrict__ scal,
                              float* __restrict__ out) {
    int i = blockIdx.x * blockDim.x + threadIdx.x;   // over B*N
    int b = i / NN;
    float W  = scal[b*5+0], Wx = scal[b*5+1], Wy = scal[b*5+2];
    float Wz = scal[b*5+3], Q  = scal[b*5+4];
    const float* p = xyz1 + (size_t)i * 3;
    float x = p[0], y = p[1], z = p[2];
    float pp = x*x + y*y + z*z;
    float dotw = x*Wx + y*Wy + z*Wz;
    float c = sl[i] * (pp * W + Q - 2.0f * dotw);
    #pragma unroll
    for (int d = 1; d < 64; d <<= 1) c += __shfl_xor(c, d);
    if ((threadIdx.x & 63) == 0)
        atomicAdd(out, c * (1.0f / (float)(BB * NN)));
}

extern "C" void kernel_launch(void* const* d_in, const int* in_sizes, int n_in,
                              void* d_out, int out_size, void* d_ws, size_t ws_size,
                              hipStream_t stream) {
    const float* xyz1 = (const float*)d_in[0];   // [B,N,3]
    const float* xyz2 = (const float*)d_in[1];   // [B,M,3]
    float* out  = (float*)d_out;                 // scalar

    float* satl  = (float*)d_ws;                 // B*N
    float* sl    = satl  + BB * NN;              // B*N
    float* satr  = sl    + BB * NN;              // B*M
    float* sr2   = satr  + BB * MM;              // B*M
    float* bsum  = sr2   + BB * MM;              // B
    float* slsum = bsum  + BB;                   // B
    float* scal  = slsum + BB;                   // B*5

    emd_init<<<(BB * NN + 255) / 256, 256, 0, stream>>>(satl, satr, bsum,
                                                        slsum, scal, out);

    const double levels[10] = {-16384.0, -4096.0, -1024.0, -256.0, -64.0,
                               -16.0, -4.0, -1.0, -0.25, 0.0};
    const double LOG2E = 1.4426950408889634;
    float c[10];
    for (int l = 0; l < 10; ++l) c[l] = (float)(levels[l] * LOG2E);

    const int grid = BB * (NN / RPB);   // 512 blocks = 2 per CU

    emd_passA<<<grid, BLK, 0, stream>>>(xyz1, xyz2, satl, satr, sl, c[0]);
    for (int l = 0; l <= 8; ++l) {
        emd_passB<<<grid, BLK, 0, stream>>>(xyz1, xyz2, sl, satr, sr2, bsum,
                                            (l == 8) ? 1 : 0, c[l]);
        if (l < 8)
            emd_passCA0<<<grid, BLK, 0, stream>>>(
                xyz1, xyz2, sl, satl, sr2, satr, out, c[l], c[l + 1]);
        else
            emd_passCA1<<<grid, BLK, 0, stream>>>(
                xyz1, xyz2, sl, satl, sr2, bsum, slsum, out, c[l]);
    }
    emd_lvl9_col<<<BB * MM / 256, 256, 0, stream>>>(xyz2, satr, slsum, scal);
    emd_lvl9_cost<<<BB * NN / 256, 256, 0, stream>>>(xyz1, sl, scal, out);
}